// Round 17
// baseline (2038.974 us; speedup 1.0000x reference)
//
#include <hip/hip_runtime.h>
#include <cstdint>
#include <cstddef>

// EventSNNFlowNetLite: 8-timestep spiking conv U-Net, fp32.
// v19 = v18 + ONE change: d1 also drops the weight ping-pong (DBW=0).
// Rationale: d1 is the kernel where the 128-VGPR occupancy quantum actually
// binds (grid 1024 = 4 blocks/CU possible, LDS 34.8KB allows 4, VGPR 156 caps
// at 3). Freeing the wB bank aims for <=128 -> 4 waves/SIMD (+33% TLP).
// d2 stays DBW=0 (verified 72.6us/VGPR148), d3 stays DBW=1.

static constexpr float THRc   = 1.0f;
static constexpr float DECAYc = 0.5f;   // 1 - 1/TAU, TAU=2

__device__ __forceinline__ float getc(const float4& v, int k) {
    switch (k & 3) {
        case 0: return v.x;
        case 1: return v.y;
        case 2: return v.z;
        default: return v.w;
    }
}

// ---------------- weight collapse prep (3x3 conv on up2 -> per-phase 2x2) ----
__global__ __launch_bounds__(256) void prep_collapse(const float* __restrict__ w,
                                                     float* __restrict__ wc, int pairs)
{
    int idx = blockIdx.x * 256 + threadIdx.x;
    if (idx >= pairs) return;
    float a[3][3];
#pragma unroll
    for (int i = 0; i < 3; ++i)
#pragma unroll
        for (int j = 0; j < 3; ++j) a[i][j] = w[idx * 9 + i * 3 + j];
    float rs[2][2][3];
#pragma unroll
    for (int kx = 0; kx < 3; ++kx) {
        rs[0][0][kx] = a[0][kx];
        rs[0][1][kx] = a[1][kx] + a[2][kx];
        rs[1][0][kx] = a[0][kx] + a[1][kx];
        rs[1][1][kx] = a[2][kx];
    }
#pragma unroll
    for (int py = 0; py < 2; ++py)
#pragma unroll
        for (int px = 0; px < 2; ++px)
#pragma unroll
            for (int r = 0; r < 2; ++r) {
                float c0, c1;
                if (px == 0) { c0 = rs[py][r][0];               c1 = rs[py][r][1] + rs[py][r][2]; }
                else         { c0 = rs[py][r][0] + rs[py][r][1]; c1 = rs[py][r][2]; }
                wc[idx * 16 + ((py * 2 + px) * 2 + r) * 2 + 0] = c0;
                wc[idx * 16 + ((py * 2 + px) * 2 + r) * 2 + 1] = c1;
            }
}

// ---------------- decoder conv: 3x3 on up2(src), phase-collapsed ------------
// Double-buffered tile; weights via VMEM-laundered dwordx4. DBW=1: ping-pong
// one ic ahead. DBW=0: serial wload->compute (lower VGPR; latency via TLP).
template<int IC, int ICC, int OC, int SIH, int SIW, int CPT, int YPB, int OCT,
         int NW, int SKIP_IC, int SKC, int DBW>
__global__ __launch_bounds__(NW * 64) void dec_conv(
    const float* __restrict__ in,     // [N][IC][SIH][SIW]
    const float* __restrict__ wc,     // [OC][IC][16] collapsed
    const float* __restrict__ bias,   // [OC]
    float* __restrict__ mem,          // [N][OC][OH][OW]
    float* __restrict__ out,          // [N][OC][OH][OW] (may be null: mem-only)
    const float* __restrict__ skip_in,// [N][SKIP_IC][OH][OW]
    const float* __restrict__ skip_w) // [OC][SKIP_IC]
{
    constexpr int NT   = NW * 64;
    constexpr int LPT  = SIW / CPT;
    static_assert((CPT & 1) == 0 && (CPT == 2 || (CPT & 3) == 0), "CPT even (2 or mult of 4)");
    static_assert(LPT * YPB == 64, "wave must tile the band");
    static_assert((ICC & 1) == 0, "ICC even for wA/wB ping-pong");
    constexpr int OC_B = NW * OCT;
    constexpr int NOCB = OC / OC_B;
    constexpr int NYB  = SIH / YPB;
    constexpr int SP   = SIW + 8;        // col s at idx s+4; zeros at idx 3, SIW+4
    constexpr int SR   = YPB + 2;
    constexpr int OH   = 2 * SIH, OW = 2 * SIW;
    constexpr int NCH  = IC / ICC;
    constexpr int W4   = SIW / 4;
    constexpr int TILE = ICC * SR * SP;
    constexpr int OROWS = 2 * YPB;
    constexpr int SKTILE = (SKIP_IC > 0) ? SKC * OROWS * OW : 0;
    constexpr int BASE = (2 * TILE) > SKTILE ? (2 * TILE) : SKTILE;
    constexpr int SLOTS = ICC * SR * W4;

    __shared__ __align__(16) float sb[BASE];

    int b = blockIdx.x;
    const int ocb = b % NOCB; b /= NOCB;
    const int yb  = b % NYB;  b /= NYB;
    const int n   = b;
    const int y0  = yb * YPB;

    const int lane = threadIdx.x & 63;
    const int wav  = threadIdx.x >> 6;
    const int cl   = lane % LPT;
    const int yp   = lane / LPT;
    const int c0   = cl * CPT;
    const int y    = y0 + yp;

    const int oc0 = __builtin_amdgcn_readfirstlane(ocb * OC_B + wav * OCT);

    // opaque zero: forces weight loads onto the VMEM (vector) path, not s_load
    int lzero;
    asm volatile("v_mov_b32 %0, 0" : "=v"(lzero));
    const float4* wlane = reinterpret_cast<const float4*>(wc) + lzero;
    const int wbase = oc0 * IC * 4;   // float4 units, wave-uniform

    // zero x-halo cols once, both buffers (interior stages never touch them)
    for (int f = threadIdx.x; f < 2 * ICC * SR * 2; f += NT) {
        int side = f & 1;
        int t    = f >> 1;
        int r    = t % SR;
        int tt   = t / SR;
        int ic   = tt % ICC;
        int buf  = tt / ICC;
        sb[buf * TILE + (ic * SR + r) * SP + (side ? (SIW + 4) : 3)] = 0.0f;
    }

    float acc[OCT][2][2 * CPT];
#pragma unroll
    for (int j = 0; j < OCT; ++j) {
        float bv = bias[oc0 + j];
#pragma unroll
        for (int py = 0; py < 2; ++py)
#pragma unroll
            for (int q = 0; q < 2 * CPT; ++q) acc[j][py][q] = bv;
    }

    const float* inn = in + (size_t)n * IC * SIH * SIW;

    auto wload = [&](int icg, float4* dst) {
#pragma unroll
        for (int j = 0; j < OCT; ++j)
#pragma unroll
            for (int g = 0; g < 4; ++g)
                dst[j * 4 + g] = wlane[wbase + (j * IC + icg) * 4 + g];
    };

    auto stage = [&](int buf, int ch) {
        const float* inb = inn + (size_t)ch * ICC * SIH * SIW;
        float* dst = sb + buf * TILE;
        for (int f = threadIdx.x; f < SLOTS; f += NT) {
            int c4 = f & (W4 - 1);
            int t  = f / W4;
            int r  = t % SR;
            int ic = t / SR;
            int sy = y0 - 1 + r;
            float4 v = make_float4(0.f, 0.f, 0.f, 0.f);
            if (sy >= 0 && sy < SIH)
                v = *reinterpret_cast<const float4*>(
                        inb + (size_t)ic * SIH * SIW + (size_t)sy * SIW + 4 * c4);
            *reinterpret_cast<float4*>(&dst[(ic * SR + r) * SP + 4 + 4 * c4]) = v;
        }
    };

    auto compute = [&](const float* bp, int icl, const float4* w) {
        float s[3][CPT + 2];
#pragma unroll
        for (int r = 0; r < 3; ++r) {
            const int rb = (icl * SR + yp + r) * SP;
            s[r][0] = bp[rb + 3 + c0];                      // left halo col c0-1
            if constexpr (CPT >= 4) {
#pragma unroll
                for (int v = 0; v < CPT / 4; ++v) {
                    float4 t4 = *reinterpret_cast<const float4*>(&bp[rb + 4 + c0 + 4 * v]);
                    s[r][1 + 4 * v] = t4.x; s[r][2 + 4 * v] = t4.y;
                    s[r][3 + 4 * v] = t4.z; s[r][4 + 4 * v] = t4.w;
                }
            } else {
                float2 t2 = *reinterpret_cast<const float2*>(&bp[rb + 4 + c0]);
                s[r][1] = t2.x; s[r][2] = t2.y;
            }
            s[r][CPT + 1] = bp[rb + 4 + c0 + CPT];          // right halo col c0+CPT
        }
#pragma unroll
        for (int j = 0; j < OCT; ++j)
#pragma unroll
            for (int py = 0; py < 2; ++py)
#pragma unroll
                for (int cc = 0; cc < CPT; ++cc)
#pragma unroll
                    for (int px = 0; px < 2; ++px) {
                        float v = acc[j][py][cc * 2 + px];
#pragma unroll
                        for (int rr = 0; rr < 2; ++rr)
#pragma unroll
                            for (int c2 = 0; c2 < 2; ++c2)
                                v += getc(w[j * 4 + py * 2 + px], rr * 2 + c2)
                                   * s[py + rr][cc + px + c2];
                        acc[j][py][cc * 2 + px] = v;
                    }
    };

    if constexpr (DBW) {
        float4 wA[OCT * 4], wB[OCT * 4];
        wload(0, wA);
        stage(0, 0);
        __syncthreads();
        for (int ch = 0; ch < NCH; ++ch) {
            if (ch + 1 < NCH) stage((ch + 1) & 1, ch + 1);   // overlap with compute
            const float* bp = sb + (ch & 1) * TILE;
            const int icg0 = ch * ICC;
            for (int ic = 0; ic < ICC; ic += 2) {
                wload(icg0 + ic + 1, wB);
                compute(bp, ic, wA);
                wload(icg0 + ic + 2, wA);   // next pair / next chunk (slack-guarded)
                compute(bp, ic + 1, wB);
            }
            __syncthreads();   // stage(ch+1) complete; compute reads of bp done
        }
    } else {
        float4 wA[OCT * 4];
        stage(0, 0);
        __syncthreads();
        for (int ch = 0; ch < NCH; ++ch) {
            if (ch + 1 < NCH) stage((ch + 1) & 1, ch + 1);   // overlap with compute
            const float* bp = sb + (ch & 1) * TILE;
            const int icg0 = ch * ICC;
            for (int ic = 0; ic < ICC; ++ic) {
                wload(icg0 + ic, wA);       // latency covered by TLP
                compute(bp, ic, wA);
            }
            __syncthreads();   // stage(ch+1) complete; compute reads of bp done
        }
    }

    // ---- fused 1x1 skip conv via LDS-staged tile (overlays sb) ----
    constexpr int NV = (2 * CPT) / 4;
    float sk[OCT][2][2 * CPT] = {};
    if constexpr (SKIP_IC > 0) {
        constexpr int NSK = SKIP_IC / SKC;
        constexpr int OW4 = OW / 4;
        const float* skn = skip_in + (size_t)n * SKIP_IC * OH * OW;
        for (int sc = 0; sc < NSK; ++sc) {
            if (sc) __syncthreads();   // prior reads of sb done (first: loop barrier)
            for (int f = threadIdx.x; f < SKC * OROWS * OW4; f += NT) {
                int c4 = f & (OW4 - 1);
                int t  = f / OW4;
                int r  = t % OROWS;
                int ic = t / OROWS;
                *reinterpret_cast<float4*>(&sb[(ic * OROWS + r) * OW + 4 * c4]) =
                    *reinterpret_cast<const float4*>(
                        skn + ((size_t)(sc * SKC + ic) * OH + 2 * y0 + r) * OW + 4 * c4);
            }
            __syncthreads();
            float wsk[OCT][SKC];
#pragma unroll
            for (int j = 0; j < OCT; ++j)
#pragma unroll
                for (int ic = 0; ic < SKC; ++ic)
                    wsk[j][ic] = skip_w[(size_t)(oc0 + j) * SKIP_IC + sc * SKC + ic];
#pragma unroll
            for (int ic = 0; ic < SKC; ++ic)
#pragma unroll
                for (int py = 0; py < 2; ++py)
#pragma unroll
                    for (int v = 0; v < NV; ++v) {
                        float4 sv = *reinterpret_cast<const float4*>(
                            &sb[(ic * OROWS + 2 * yp + py) * OW + 2 * c0 + 4 * v]);
#pragma unroll
                        for (int j = 0; j < OCT; ++j) {
                            sk[j][py][4 * v + 0] += wsk[j][ic] * sv.x;
                            sk[j][py][4 * v + 1] += wsk[j][ic] * sv.y;
                            sk[j][py][4 * v + 2] += wsk[j][ic] * sv.z;
                            sk[j][py][4 * v + 3] += wsk[j][ic] * sv.w;
                        }
                    }
        }
    }

    // ---- LIF epilogue (float4) ----
    const bool wout = (out != nullptr);
#pragma unroll
    for (int j = 0; j < OCT; ++j)
#pragma unroll
        for (int py = 0; py < 2; ++py) {
            size_t ob = (((size_t)n * OC + oc0 + j) * OH + (2 * y + py)) * OW + 2 * c0;
#pragma unroll
            for (int v = 0; v < NV; ++v) {
                float4 mv = *reinterpret_cast<const float4*>(&mem[ob + 4 * v]);
                float4 ov, nm;
                float m0 = mv.x * DECAYc + acc[j][py][4 * v + 0];
                float m1 = mv.y * DECAYc + acc[j][py][4 * v + 1];
                float m2 = mv.z * DECAYc + acc[j][py][4 * v + 2];
                float m3 = mv.w * DECAYc + acc[j][py][4 * v + 3];
                float s0 = (m0 - THRc) > 0.0f ? 1.0f : 0.0f;
                float s1 = (m1 - THRc) > 0.0f ? 1.0f : 0.0f;
                float s2 = (m2 - THRc) > 0.0f ? 1.0f : 0.0f;
                float s3 = (m3 - THRc) > 0.0f ? 1.0f : 0.0f;
                nm.x = m0 - s0 * THRc; nm.y = m1 - s1 * THRc;
                nm.z = m2 - s2 * THRc; nm.w = m3 - s3 * THRc;
                *reinterpret_cast<float4*>(&mem[ob + 4 * v]) = nm;
                if (wout) {
                    ov.x = s0 + sk[j][py][4 * v + 0];
                    ov.y = s1 + sk[j][py][4 * v + 1];
                    ov.z = s2 + sk[j][py][4 * v + 2];
                    ov.w = s3 + sk[j][py][4 * v + 3];
                    *reinterpret_cast<float4*>(&out[ob + 4 * v]) = ov;
                }
            }
        }
}

// ---------------- encoder conv v1: KxK stride-2 (e1 only) -------------------
template<int IC, int ICC, int OC, int IH, int IW, int K, int CPT, int LPT, int OCT, bool DO_MEAN>
__global__ __launch_bounds__(256) void enc_conv(
    const float* __restrict__ in, int in_nstride,
    const float* __restrict__ wgt,   // [OC][IC][K][K]
    const float* __restrict__ bias,  // [OC]
    float* __restrict__ mem,
    float* __restrict__ out,
    float* __restrict__ mean,
    float inv_tf)
{
    constexpr int P    = K / 2;
    constexpr int OH   = IH / 2, OW = IW / 2;
    constexpr int SPr  = 4 + IW + P;
    constexpr int SP   = (SPr + 3) & ~3;
    constexpr int OC_B = 4 * OCT;
    constexpr int NOCB = OC / OC_B;
    constexpr int RL   = 2 * CPT + 2 * P - 1;
    constexpr int NCH  = IC / ICC;
    constexpr int W4   = IW / 4;
    static_assert(LPT * CPT == OW, "lanes x CPT must cover OW");
    static_assert((ICC & (ICC - 1)) == 0, "ICC pow2");

    __shared__ float sb[K][ICC][SP];

    int b = blockIdx.x;
    const int ocb = b % NOCB; b /= NOCB;
    const int y   = b % OH;   b /= OH;
    const int n   = b;

    const int lane = threadIdx.x & 63;
    const int wav  = threadIdx.x >> 6;
    const int x0   = (lane % LPT) * CPT;   // lanes >= LPT duplicate, epilogue guarded
    const int oc0  = __builtin_amdgcn_readfirstlane(ocb * OC_B + wav * OCT);

    // zero x-halo cols once
    for (int f = threadIdx.x; f < K * ICC * 2 * P; f += 256) {
        int h  = f % (2 * P);
        int t  = f / (2 * P);
        int ic = t & (ICC - 1);
        int r  = t / ICC;
        int col = (h < P) ? (4 - P + h) : (4 + IW + h - P);
        sb[r][ic][col] = 0.0f;
    }

    float acc[OCT][CPT];
#pragma unroll
    for (int j = 0; j < OCT; ++j) {
        float bv = bias[oc0 + j];
#pragma unroll
        for (int cc = 0; cc < CPT; ++cc) acc[j][cc] = bv;
    }

    const float* inn = in + (size_t)n * (size_t)in_nstride;

    for (int ch = 0; ch < NCH; ++ch) {
        __syncthreads();
        // ---- stage tile: float4 interior, per-row predicate only ----
        const float* inb = inn + (size_t)ch * ICC * IH * IW;
        constexpr int SLOTS = K * ICC * W4;
        for (int f = threadIdx.x; f < SLOTS; f += 256) {
            int c4 = f & (W4 - 1);
            int t  = f / W4;
            int ic = t & (ICC - 1);
            int r  = t / ICC;
            int sy = 2 * y - P + r;
            float4 v = make_float4(0.f, 0.f, 0.f, 0.f);
            if (sy >= 0 && sy < IH)
                v = *reinterpret_cast<const float4*>(
                        inb + (size_t)ic * IH * IW + (size_t)sy * IW + 4 * c4);
            *reinterpret_cast<float4*>(&sb[r][ic][4 + 4 * c4]) = v;
        }
        __syncthreads();
        // ---- accumulate ----
        for (int ic = 0; ic < ICC; ++ic) {
            float s[K][RL];
#pragma unroll
            for (int r = 0; r < K; ++r)
#pragma unroll
                for (int k = 0; k < RL; ++k)
                    s[r][k] = sb[r][ic][4 - P + 2 * x0 + k];
            const float* wp = wgt + ((size_t)oc0 * IC + ch * ICC + ic) * (K * K);
#pragma unroll
            for (int j = 0; j < OCT; ++j) {
                float wv[K * K];
#pragma unroll
                for (int k = 0; k < K * K; ++k) wv[k] = wp[(size_t)j * IC * K * K + k];
#pragma unroll
                for (int cc = 0; cc < CPT; ++cc)
#pragma unroll
                    for (int ky = 0; ky < K; ++ky)
#pragma unroll
                        for (int kx = 0; kx < K; ++kx)
                            acc[j][cc] += wv[ky * K + kx] * s[ky][2 * cc + kx];
            }
        }
    }

    if (lane < LPT) {
#pragma unroll
        for (int j = 0; j < OCT; ++j) {
            size_t ob = (((size_t)n * OC + oc0 + j) * OH + y) * OW + x0;
#pragma unroll
            for (int cc = 0; cc < CPT; ++cc) {
                float m  = mem[ob + cc] * DECAYc + acc[j][cc];
                float sp = (m - THRc) > 0.0f ? 1.0f : 0.0f;
                mem[ob + cc] = m - sp * THRc;
                if constexpr (DO_MEAN) {
                    float mv = mean[ob + cc];
                    mean[ob + cc] = mv + (sp - mv) * inv_tf;
                }
                out[ob + cc] = sp;
            }
        }
    }
}

// ---------------- encoder conv dbuf: 3x3 stride-2, s_load weights -----------
template<int IC, int ICC, int OC, int IH, int IW, int CPT, int LPT, int OCT, bool DO_MEAN>
__global__ __launch_bounds__(256) void enc_convdb(
    const float* __restrict__ in, int in_nstride,
    const float* __restrict__ wgt,   // [OC][IC][3][3]
    const float* __restrict__ bias,  // [OC]
    float* __restrict__ mem,
    float* __restrict__ out,
    float* __restrict__ mean,
    float inv_tf)
{
    constexpr int K    = 3;
    constexpr int P    = 1;
    constexpr int OH   = IH / 2, OW = IW / 2;
    constexpr int SPr  = 4 + IW + P;
    constexpr int SP   = (SPr + 3) & ~3;
    constexpr int OC_B = 4 * OCT;
    constexpr int NOCB = OC / OC_B;
    constexpr int RL   = 2 * CPT + 2 * P - 1;
    constexpr int NCH  = IC / ICC;
    constexpr int W4   = IW / 4;
    constexpr int TILE = K * ICC * SP;
    constexpr int SLOTS = K * ICC * W4;
    static_assert(LPT * CPT == OW, "lanes x CPT must cover OW");
    static_assert((ICC & (ICC - 1)) == 0, "ICC pow2");
    static_assert(NCH >= 2, "dbuf needs >=2 chunks");

    __shared__ __align__(16) float sb[2 * TILE];

    int b = blockIdx.x;
    const int ocb = b % NOCB; b /= NOCB;
    const int y   = b % OH;   b /= OH;
    const int n   = b;

    const int lane = threadIdx.x & 63;
    const int wav  = threadIdx.x >> 6;
    const int x0   = (lane % LPT) * CPT;   // lanes >= LPT duplicate, epilogue guarded
    const int oc0  = __builtin_amdgcn_readfirstlane(ocb * OC_B + wav * OCT);

    // zero x-halo cols once, both buffers
    for (int f = threadIdx.x; f < 2 * K * ICC * 2 * P; f += 256) {
        int h   = f % (2 * P);
        int t   = f / (2 * P);
        int ic  = t & (ICC - 1);
        int t2  = t / ICC;
        int r   = t2 % K;
        int buf = t2 / K;
        int col = (h < P) ? (4 - P + h) : (4 + IW + h - P);
        sb[buf * TILE + (r * ICC + ic) * SP + col] = 0.0f;
    }

    float acc[OCT][CPT];
#pragma unroll
    for (int j = 0; j < OCT; ++j) {
        float bv = bias[oc0 + j];
#pragma unroll
        for (int cc = 0; cc < CPT; ++cc) acc[j][cc] = bv;
    }

    const float* inn = in + (size_t)n * (size_t)in_nstride;

    auto stage = [&](int buf, int ch) {
        const float* inb = inn + (size_t)ch * ICC * IH * IW;
        float* dst = sb + buf * TILE;
        for (int f = threadIdx.x; f < SLOTS; f += 256) {
            int c4 = f & (W4 - 1);
            int t  = f / W4;
            int ic = t & (ICC - 1);
            int r  = t / ICC;
            int sy = 2 * y - P + r;
            float4 v = make_float4(0.f, 0.f, 0.f, 0.f);
            if (sy >= 0 && sy < IH)
                v = *reinterpret_cast<const float4*>(
                        inb + (size_t)ic * IH * IW + (size_t)sy * IW + 4 * c4);
            *reinterpret_cast<float4*>(&dst[(r * ICC + ic) * SP + 4 + 4 * c4]) = v;
        }
    };

    stage(0, 0);
    __syncthreads();
    for (int ch = 0; ch < NCH; ++ch) {
        if (ch + 1 < NCH) stage((ch + 1) & 1, ch + 1);   // overlap with compute
        const float* bp = sb + (ch & 1) * TILE;
        for (int ic = 0; ic < ICC; ++ic) {
            float s[K][RL];
#pragma unroll
            for (int r = 0; r < K; ++r)
#pragma unroll
                for (int k = 0; k < RL; ++k)
                    s[r][k] = bp[(r * ICC + ic) * SP + 4 - P + 2 * x0 + k];
            const float* wp = wgt + ((size_t)oc0 * IC + ch * ICC + ic) * (K * K);
#pragma unroll
            for (int j = 0; j < OCT; ++j) {
                float wv[K * K];
#pragma unroll
                for (int k = 0; k < K * K; ++k) wv[k] = wp[(size_t)j * IC * K * K + k];
#pragma unroll
                for (int cc = 0; cc < CPT; ++cc)
#pragma unroll
                    for (int ky = 0; ky < K; ++ky)
#pragma unroll
                        for (int kx = 0; kx < K; ++kx)
                            acc[j][cc] += wv[ky * K + kx] * s[ky][2 * cc + kx];
            }
        }
        __syncthreads();   // stage(ch+1) complete; compute reads of bp done
    }

    if (lane < LPT) {
#pragma unroll
        for (int j = 0; j < OCT; ++j) {
            size_t ob = (((size_t)n * OC + oc0 + j) * OH + y) * OW + x0;
#pragma unroll
            for (int cc = 0; cc < CPT; ++cc) {
                float m  = mem[ob + cc] * DECAYc + acc[j][cc];
                float sp = (m - THRc) > 0.0f ? 1.0f : 0.0f;
                mem[ob + cc] = m - sp * THRc;
                if constexpr (DO_MEAN) {
                    float mv = mean[ob + cc];
                    mean[ob + cc] = mv + (sp - mv) * inv_tf;
                }
                out[ob + cc] = sp;
            }
        }
    }
}

// ---------------- generic conv (flow head only) ------------------------------
template<int IC, int OC, int IH, int IW, int OH, int OW,
         int K, int STRIDE, int PAD, bool UP2, int SKIP_IC,
         bool DO_LIF, bool DO_MEAN>
__global__ __launch_bounds__(256) void conv_fused(
    const float* __restrict__ in, int in_nstride,
    const float* __restrict__ wgt,
    const float* __restrict__ bias,
    float* __restrict__ mem,
    float* __restrict__ out,
    const float* __restrict__ skip_in,
    const float* __restrict__ skip_w,
    float* __restrict__ mean,
    float inv_tf, float outscale)
{
    constexpr int VEC  = 4;
    constexpr int OWV  = OW / VEC;
    constexpr int WSZ  = IC * K * K;
    constexpr int SIH  = UP2 ? IH / 2 : IH;
    constexpr int SIW  = UP2 ? IW / 2 : IW;
    constexpr int RLEN = (VEC - 1) * STRIDE + K;

    __shared__ float sw[WSZ];

    const int bstart = blockIdx.x * 256;
    const int oc = (bstart / (OH * OWV)) % OC;

    for (int i = threadIdx.x; i < WSZ; i += 256) sw[i] = wgt[oc * WSZ + i];
    __syncthreads();

    const int idx = bstart + threadIdx.x;
    const int wx  = idx % OWV;
    int tt        = idx / OWV;
    const int oy  = tt % OH; tt /= OH;
    tt /= OC;
    const int n   = tt;
    const int ox0 = wx * VEC;

    const float bv = bias ? bias[oc] : 0.0f;
    float acc[VEC];
#pragma unroll
    for (int v = 0; v < VEC; ++v) acc[v] = bv;

    const float* inn = in + (size_t)n * (size_t)in_nstride;

    for (int ic = 0; ic < IC; ++ic) {
        const float* inc = inn + (size_t)ic * (SIH * SIW);
#pragma unroll
        for (int ky = 0; ky < K; ++ky) {
            const int uy = oy * STRIDE + ky - PAD;
            const bool rowok = (uy >= 0) & (uy < IH);
            int sy = UP2 ? (uy >> 1) : uy;
            sy = sy < 0 ? 0 : (sy > SIH - 1 ? SIH - 1 : sy);
            const float* __restrict__ row = inc + (size_t)sy * SIW;

            float r[RLEN];
#pragma unroll
            for (int j = 0; j < RLEN; ++j) {
                const int ux = ox0 * STRIDE - PAD + j;
                const bool ok = rowok & (ux >= 0) & (ux < IW);
                int sx = UP2 ? (ux >> 1) : ux;
                sx = sx < 0 ? 0 : (sx > SIW - 1 ? SIW - 1 : sx);
                r[j] = ok ? row[sx] : 0.0f;
            }
#pragma unroll
            for (int kx = 0; kx < K; ++kx) {
                const float wv = sw[(ic * K + ky) * K + kx];
#pragma unroll
                for (int v = 0; v < VEC; ++v)
                    acc[v] += r[v * STRIDE + kx] * wv;
            }
        }
    }

    const size_t obase = ((((size_t)n * OC + oc) * OH) + oy) * (size_t)OW + ox0;
#pragma unroll
    for (int v = 0; v < VEC; ++v) out[obase + v] = acc[v] * outscale;
}

extern "C" void kernel_launch(void* const* d_in, const int* in_sizes, int n_in,
                              void* d_out, int out_size, void* d_ws, size_t ws_size,
                              hipStream_t stream)
{
    const float* x     = (const float*)d_in[0];
    const float* w_e1  = (const float*)d_in[1];
    const float* b_e1  = (const float*)d_in[2];
    const float* w_e2  = (const float*)d_in[3];
    const float* b_e2  = (const float*)d_in[4];
    const float* w_e3  = (const float*)d_in[5];
    const float* b_e3  = (const float*)d_in[6];
    const float* w_d3  = (const float*)d_in[7];
    const float* b_d3  = (const float*)d_in[8];
    const float* w_d2  = (const float*)d_in[9];
    const float* b_d2  = (const float*)d_in[10];
    const float* w_d1  = (const float*)d_in[11];
    const float* b_d1  = (const float*)d_in[12];
    const float* w_sk2 = (const float*)d_in[13];
    const float* w_sk1 = (const float*)d_in[14];
    const float* w_fl  = (const float*)d_in[15];
    const float* b_fl  = (const float*)d_in[16];
    float* outp = (float*)d_out;

    float* ws = (float*)d_ws;
    size_t off = 0;
    auto alloc = [&](size_t nelem) { float* p = ws + off; off += nelem; return p; };

    // persistent state (zeroed each launch)
    float* m1  = alloc(4UL * 32 * 128 * 128);
    float* m2  = alloc(4UL * 64 * 64 * 64);
    float* m3  = alloc(4UL * 128 * 32 * 32);
    float* md3 = alloc(4UL * 64 * 64 * 64);
    float* md2 = alloc(4UL * 32 * 128 * 128);
    float* md1 = alloc(4UL * 32 * 256 * 256);
    float* me1 = alloc(4UL * 32 * 128 * 128);
    float* me2 = alloc(4UL * 64 * 64 * 64);
    const size_t zcount = off;
    // per-timestep activations
    float* s1  = alloc(4UL * 32 * 128 * 128);
    float* s2  = alloc(4UL * 64 * 64 * 64);
    float* s3  = alloc(4UL * 128 * 32 * 32);
    float* d3a = alloc(4UL * 64 * 64 * 64);
    float* d2a = alloc(4UL * 32 * 128 * 128);
    float* d1a = alloc(4UL * 32 * 256 * 256);
    // collapsed decoder weights (+64 floats slack each for prefetch overshoot)
    float* wc3 = alloc(64UL * 128 * 16 + 64);
    float* wc2 = alloc(32UL * 64 * 16 + 64);
    float* wc1 = alloc(32UL * 32 * 16 + 64);
    (void)ws_size; (void)in_sizes; (void)n_in; (void)out_size;

    hipMemsetAsync(d_ws, 0, zcount * sizeof(float), stream);

    prep_collapse<<<(64 * 128 + 255) / 256, 256, 0, stream>>>(w_d3, wc3, 64 * 128);
    prep_collapse<<<(32 * 64 + 255) / 256, 256, 0, stream>>>(w_d2, wc2, 32 * 64);
    prep_collapse<<<(32 * 32 + 255) / 256, 256, 0, stream>>>(w_d1, wc1, 32 * 32);

    for (int t = 0; t < 8; ++t) {
        const float inv_tf = 1.0f / (float)(t + 1);
        const float* xt = x + (size_t)t * 2 * 256 * 256;   // n-stride = T*2*H*W

        // e1: 5x5 s2, 2->32, 256->128, LIF + me1
        enc_conv<2, 2, 32, 256, 256, 5, 2, 64, 2, true>
            <<<4 * 128 * 4, 256, 0, stream>>>(xt, 8 * 2 * 256 * 256, w_e1, b_e1,
                                              m1, s1, me1, inv_tf);
        // e2: 3x3 s2, 32->64, 128->64, LIF + me2. dbuf ICC=8 (26.1KB), grid 2048
        enc_convdb<32, 8, 64, 128, 128, 1, 64, 2, true>
            <<<4 * 64 * 8, 256, 0, stream>>>(s1, 32 * 128 * 128, w_e2, b_e2,
                                             m2, s2, me2, inv_tf);
        // e3: 3x3 s2, 64->128, 64->32, LIF. dbuf ICC=16 (27.6KB), grid 1024
        enc_convdb<64, 16, 128, 64, 64, 1, 32, 4, false>
            <<<4 * 32 * 8, 256, 0, stream>>>(s2, 64 * 64 * 64, w_e3, b_e3,
                                             m3, s3, nullptr, inv_tf);
        // d3: ICC=16 (dbuf 30.7KB), OCT=1, CPT=2, YPB=4, NW=4, DBW=1. grid 512
        dec_conv<128, 16, 64, 32, 32, 2, 4, 1, 4, 64, 8, 1>
            <<<4 * 8 * 16, 256, 0, stream>>>(s3, wc3, b_d3, md3, d3a, me2, w_sk2);
        // d2: ICC=16 (dbuf 36.9KB), OCT=2, CPT=2, YPB=2, NW=4, DBW=0. grid 512
        dec_conv<64, 16, 32, 64, 64, 2, 2, 2, 4, 32, 8, 0>
            <<<4 * 32 * 4, 256, 0, stream>>>(d3a, wc2, b_d2, md2, d2a, me1, w_sk1);
        // d1: ICC=8 (dbuf 34.8KB), OCT=2, CPT=4, YPB=2, LPT=32, DBW=0 (target
        // VGPR <=128 -> 4 blocks/CU resident). grid 1024
        dec_conv<32, 8, 32, 128, 128, 4, 2, 2, 4, 0, 1, 0>
            <<<4 * 64 * 4, 256, 0, stream>>>(d2a, wc1, b_d1, md1,
                                             (t == 7) ? d1a : nullptr, nullptr, nullptr);
        // flow head only at the final timestep
        if (t == 7) {
            conv_fused<32, 2, 256, 256, 256, 256, 3, 1, 1, false, 0, false, false>
                <<<512, 256, 0, stream>>>(d1a, 32 * 256 * 256, w_fl, b_fl,
                                          nullptr, outp, nullptr, nullptr, nullptr, inv_tf, 16.0f);
        }
    }
}

// Round 18
// 2019.233 us; speedup vs baseline: 1.0098x; 1.0098x over previous
//
#include <hip/hip_runtime.h>
#include <cstdint>
#include <cstddef>

// EventSNNFlowNetLite: 8-timestep spiking conv U-Net, fp32.
// v20 = v18 restore (session-best verified: 2023 us; 27% faster than the
// 2772 us session start). Final configuration:
//  - decoders: dbuf input staging; VMEM-laundered weights (d3/d1 ping-pong
//    DBW=1, d2 serial DBW=0 -> VGPR 148, best measured); CPT=4 for d1,
//    CPT=2 for d2/d3; OCT<=2 family (other shapes spill).
//  - encoders: dbuf staging (e2/e3) + s_load weights; e1 single-buffer (IC=2).
//  - d1a written only at t=7; flow head once.
//  - Exhausted/refuted: grid-union fusion (3x), OCT/NW/ICC reshapes,
//    occupancy-quantum via DBW=0 on d1/d2 (floor ~148 VGPR), CPT=8 (bank
//    conflicts), LDS/s_load weight paths in decoders.

static constexpr float THRc   = 1.0f;
static constexpr float DECAYc = 0.5f;   // 1 - 1/TAU, TAU=2

__device__ __forceinline__ float getc(const float4& v, int k) {
    switch (k & 3) {
        case 0: return v.x;
        case 1: return v.y;
        case 2: return v.z;
        default: return v.w;
    }
}

// ---------------- weight collapse prep (3x3 conv on up2 -> per-phase 2x2) ----
__global__ __launch_bounds__(256) void prep_collapse(const float* __restrict__ w,
                                                     float* __restrict__ wc, int pairs)
{
    int idx = blockIdx.x * 256 + threadIdx.x;
    if (idx >= pairs) return;
    float a[3][3];
#pragma unroll
    for (int i = 0; i < 3; ++i)
#pragma unroll
        for (int j = 0; j < 3; ++j) a[i][j] = w[idx * 9 + i * 3 + j];
    float rs[2][2][3];
#pragma unroll
    for (int kx = 0; kx < 3; ++kx) {
        rs[0][0][kx] = a[0][kx];
        rs[0][1][kx] = a[1][kx] + a[2][kx];
        rs[1][0][kx] = a[0][kx] + a[1][kx];
        rs[1][1][kx] = a[2][kx];
    }
#pragma unroll
    for (int py = 0; py < 2; ++py)
#pragma unroll
        for (int px = 0; px < 2; ++px)
#pragma unroll
            for (int r = 0; r < 2; ++r) {
                float c0, c1;
                if (px == 0) { c0 = rs[py][r][0];               c1 = rs[py][r][1] + rs[py][r][2]; }
                else         { c0 = rs[py][r][0] + rs[py][r][1]; c1 = rs[py][r][2]; }
                wc[idx * 16 + ((py * 2 + px) * 2 + r) * 2 + 0] = c0;
                wc[idx * 16 + ((py * 2 + px) * 2 + r) * 2 + 1] = c1;
            }
}

// ---------------- decoder conv: 3x3 on up2(src), phase-collapsed ------------
// Double-buffered tile; weights via VMEM-laundered dwordx4. DBW=1: ping-pong
// one ic ahead. DBW=0: serial wload->compute (lower VGPR; latency via TLP).
template<int IC, int ICC, int OC, int SIH, int SIW, int CPT, int YPB, int OCT,
         int NW, int SKIP_IC, int SKC, int DBW>
__global__ __launch_bounds__(NW * 64) void dec_conv(
    const float* __restrict__ in,     // [N][IC][SIH][SIW]
    const float* __restrict__ wc,     // [OC][IC][16] collapsed
    const float* __restrict__ bias,   // [OC]
    float* __restrict__ mem,          // [N][OC][OH][OW]
    float* __restrict__ out,          // [N][OC][OH][OW] (may be null: mem-only)
    const float* __restrict__ skip_in,// [N][SKIP_IC][OH][OW]
    const float* __restrict__ skip_w) // [OC][SKIP_IC]
{
    constexpr int NT   = NW * 64;
    constexpr int LPT  = SIW / CPT;
    static_assert((CPT & 1) == 0 && (CPT == 2 || (CPT & 3) == 0), "CPT even (2 or mult of 4)");
    static_assert(LPT * YPB == 64, "wave must tile the band");
    static_assert((ICC & 1) == 0, "ICC even for wA/wB ping-pong");
    constexpr int OC_B = NW * OCT;
    constexpr int NOCB = OC / OC_B;
    constexpr int NYB  = SIH / YPB;
    constexpr int SP   = SIW + 8;        // col s at idx s+4; zeros at idx 3, SIW+4
    constexpr int SR   = YPB + 2;
    constexpr int OH   = 2 * SIH, OW = 2 * SIW;
    constexpr int NCH  = IC / ICC;
    constexpr int W4   = SIW / 4;
    constexpr int TILE = ICC * SR * SP;
    constexpr int OROWS = 2 * YPB;
    constexpr int SKTILE = (SKIP_IC > 0) ? SKC * OROWS * OW : 0;
    constexpr int BASE = (2 * TILE) > SKTILE ? (2 * TILE) : SKTILE;
    constexpr int SLOTS = ICC * SR * W4;

    __shared__ __align__(16) float sb[BASE];

    int b = blockIdx.x;
    const int ocb = b % NOCB; b /= NOCB;
    const int yb  = b % NYB;  b /= NYB;
    const int n   = b;
    const int y0  = yb * YPB;

    const int lane = threadIdx.x & 63;
    const int wav  = threadIdx.x >> 6;
    const int cl   = lane % LPT;
    const int yp   = lane / LPT;
    const int c0   = cl * CPT;
    const int y    = y0 + yp;

    const int oc0 = __builtin_amdgcn_readfirstlane(ocb * OC_B + wav * OCT);

    // opaque zero: forces weight loads onto the VMEM (vector) path, not s_load
    int lzero;
    asm volatile("v_mov_b32 %0, 0" : "=v"(lzero));
    const float4* wlane = reinterpret_cast<const float4*>(wc) + lzero;
    const int wbase = oc0 * IC * 4;   // float4 units, wave-uniform

    // zero x-halo cols once, both buffers (interior stages never touch them)
    for (int f = threadIdx.x; f < 2 * ICC * SR * 2; f += NT) {
        int side = f & 1;
        int t    = f >> 1;
        int r    = t % SR;
        int tt   = t / SR;
        int ic   = tt % ICC;
        int buf  = tt / ICC;
        sb[buf * TILE + (ic * SR + r) * SP + (side ? (SIW + 4) : 3)] = 0.0f;
    }

    float acc[OCT][2][2 * CPT];
#pragma unroll
    for (int j = 0; j < OCT; ++j) {
        float bv = bias[oc0 + j];
#pragma unroll
        for (int py = 0; py < 2; ++py)
#pragma unroll
            for (int q = 0; q < 2 * CPT; ++q) acc[j][py][q] = bv;
    }

    const float* inn = in + (size_t)n * IC * SIH * SIW;

    auto wload = [&](int icg, float4* dst) {
#pragma unroll
        for (int j = 0; j < OCT; ++j)
#pragma unroll
            for (int g = 0; g < 4; ++g)
                dst[j * 4 + g] = wlane[wbase + (j * IC + icg) * 4 + g];
    };

    auto stage = [&](int buf, int ch) {
        const float* inb = inn + (size_t)ch * ICC * SIH * SIW;
        float* dst = sb + buf * TILE;
        for (int f = threadIdx.x; f < SLOTS; f += NT) {
            int c4 = f & (W4 - 1);
            int t  = f / W4;
            int r  = t % SR;
            int ic = t / SR;
            int sy = y0 - 1 + r;
            float4 v = make_float4(0.f, 0.f, 0.f, 0.f);
            if (sy >= 0 && sy < SIH)
                v = *reinterpret_cast<const float4*>(
                        inb + (size_t)ic * SIH * SIW + (size_t)sy * SIW + 4 * c4);
            *reinterpret_cast<float4*>(&dst[(ic * SR + r) * SP + 4 + 4 * c4]) = v;
        }
    };

    auto compute = [&](const float* bp, int icl, const float4* w) {
        float s[3][CPT + 2];
#pragma unroll
        for (int r = 0; r < 3; ++r) {
            const int rb = (icl * SR + yp + r) * SP;
            s[r][0] = bp[rb + 3 + c0];                      // left halo col c0-1
            if constexpr (CPT >= 4) {
#pragma unroll
                for (int v = 0; v < CPT / 4; ++v) {
                    float4 t4 = *reinterpret_cast<const float4*>(&bp[rb + 4 + c0 + 4 * v]);
                    s[r][1 + 4 * v] = t4.x; s[r][2 + 4 * v] = t4.y;
                    s[r][3 + 4 * v] = t4.z; s[r][4 + 4 * v] = t4.w;
                }
            } else {
                float2 t2 = *reinterpret_cast<const float2*>(&bp[rb + 4 + c0]);
                s[r][1] = t2.x; s[r][2] = t2.y;
            }
            s[r][CPT + 1] = bp[rb + 4 + c0 + CPT];          // right halo col c0+CPT
        }
#pragma unroll
        for (int j = 0; j < OCT; ++j)
#pragma unroll
            for (int py = 0; py < 2; ++py)
#pragma unroll
                for (int cc = 0; cc < CPT; ++cc)
#pragma unroll
                    for (int px = 0; px < 2; ++px) {
                        float v = acc[j][py][cc * 2 + px];
#pragma unroll
                        for (int rr = 0; rr < 2; ++rr)
#pragma unroll
                            for (int c2 = 0; c2 < 2; ++c2)
                                v += getc(w[j * 4 + py * 2 + px], rr * 2 + c2)
                                   * s[py + rr][cc + px + c2];
                        acc[j][py][cc * 2 + px] = v;
                    }
    };

    if constexpr (DBW) {
        float4 wA[OCT * 4], wB[OCT * 4];
        wload(0, wA);
        stage(0, 0);
        __syncthreads();
        for (int ch = 0; ch < NCH; ++ch) {
            if (ch + 1 < NCH) stage((ch + 1) & 1, ch + 1);   // overlap with compute
            const float* bp = sb + (ch & 1) * TILE;
            const int icg0 = ch * ICC;
            for (int ic = 0; ic < ICC; ic += 2) {
                wload(icg0 + ic + 1, wB);
                compute(bp, ic, wA);
                wload(icg0 + ic + 2, wA);   // next pair / next chunk (slack-guarded)
                compute(bp, ic + 1, wB);
            }
            __syncthreads();   // stage(ch+1) complete; compute reads of bp done
        }
    } else {
        float4 wA[OCT * 4];
        stage(0, 0);
        __syncthreads();
        for (int ch = 0; ch < NCH; ++ch) {
            if (ch + 1 < NCH) stage((ch + 1) & 1, ch + 1);   // overlap with compute
            const float* bp = sb + (ch & 1) * TILE;
            const int icg0 = ch * ICC;
            for (int ic = 0; ic < ICC; ++ic) {
                wload(icg0 + ic, wA);       // latency covered by TLP
                compute(bp, ic, wA);
            }
            __syncthreads();   // stage(ch+1) complete; compute reads of bp done
        }
    }

    // ---- fused 1x1 skip conv via LDS-staged tile (overlays sb) ----
    constexpr int NV = (2 * CPT) / 4;
    float sk[OCT][2][2 * CPT] = {};
    if constexpr (SKIP_IC > 0) {
        constexpr int NSK = SKIP_IC / SKC;
        constexpr int OW4 = OW / 4;
        const float* skn = skip_in + (size_t)n * SKIP_IC * OH * OW;
        for (int sc = 0; sc < NSK; ++sc) {
            if (sc) __syncthreads();   // prior reads of sb done (first: loop barrier)
            for (int f = threadIdx.x; f < SKC * OROWS * OW4; f += NT) {
                int c4 = f & (OW4 - 1);
                int t  = f / OW4;
                int r  = t % OROWS;
                int ic = t / OROWS;
                *reinterpret_cast<float4*>(&sb[(ic * OROWS + r) * OW + 4 * c4]) =
                    *reinterpret_cast<const float4*>(
                        skn + ((size_t)(sc * SKC + ic) * OH + 2 * y0 + r) * OW + 4 * c4);
            }
            __syncthreads();
            float wsk[OCT][SKC];
#pragma unroll
            for (int j = 0; j < OCT; ++j)
#pragma unroll
                for (int ic = 0; ic < SKC; ++ic)
                    wsk[j][ic] = skip_w[(size_t)(oc0 + j) * SKIP_IC + sc * SKC + ic];
#pragma unroll
            for (int ic = 0; ic < SKC; ++ic)
#pragma unroll
                for (int py = 0; py < 2; ++py)
#pragma unroll
                    for (int v = 0; v < NV; ++v) {
                        float4 sv = *reinterpret_cast<const float4*>(
                            &sb[(ic * OROWS + 2 * yp + py) * OW + 2 * c0 + 4 * v]);
#pragma unroll
                        for (int j = 0; j < OCT; ++j) {
                            sk[j][py][4 * v + 0] += wsk[j][ic] * sv.x;
                            sk[j][py][4 * v + 1] += wsk[j][ic] * sv.y;
                            sk[j][py][4 * v + 2] += wsk[j][ic] * sv.z;
                            sk[j][py][4 * v + 3] += wsk[j][ic] * sv.w;
                        }
                    }
        }
    }

    // ---- LIF epilogue (float4) ----
    const bool wout = (out != nullptr);
#pragma unroll
    for (int j = 0; j < OCT; ++j)
#pragma unroll
        for (int py = 0; py < 2; ++py) {
            size_t ob = (((size_t)n * OC + oc0 + j) * OH + (2 * y + py)) * OW + 2 * c0;
#pragma unroll
            for (int v = 0; v < NV; ++v) {
                float4 mv = *reinterpret_cast<const float4*>(&mem[ob + 4 * v]);
                float4 ov, nm;
                float m0 = mv.x * DECAYc + acc[j][py][4 * v + 0];
                float m1 = mv.y * DECAYc + acc[j][py][4 * v + 1];
                float m2 = mv.z * DECAYc + acc[j][py][4 * v + 2];
                float m3 = mv.w * DECAYc + acc[j][py][4 * v + 3];
                float s0 = (m0 - THRc) > 0.0f ? 1.0f : 0.0f;
                float s1 = (m1 - THRc) > 0.0f ? 1.0f : 0.0f;
                float s2 = (m2 - THRc) > 0.0f ? 1.0f : 0.0f;
                float s3 = (m3 - THRc) > 0.0f ? 1.0f : 0.0f;
                nm.x = m0 - s0 * THRc; nm.y = m1 - s1 * THRc;
                nm.z = m2 - s2 * THRc; nm.w = m3 - s3 * THRc;
                *reinterpret_cast<float4*>(&mem[ob + 4 * v]) = nm;
                if (wout) {
                    ov.x = s0 + sk[j][py][4 * v + 0];
                    ov.y = s1 + sk[j][py][4 * v + 1];
                    ov.z = s2 + sk[j][py][4 * v + 2];
                    ov.w = s3 + sk[j][py][4 * v + 3];
                    *reinterpret_cast<float4*>(&out[ob + 4 * v]) = ov;
                }
            }
        }
}

// ---------------- encoder conv v1: KxK stride-2 (e1 only) -------------------
template<int IC, int ICC, int OC, int IH, int IW, int K, int CPT, int LPT, int OCT, bool DO_MEAN>
__global__ __launch_bounds__(256) void enc_conv(
    const float* __restrict__ in, int in_nstride,
    const float* __restrict__ wgt,   // [OC][IC][K][K]
    const float* __restrict__ bias,  // [OC]
    float* __restrict__ mem,
    float* __restrict__ out,
    float* __restrict__ mean,
    float inv_tf)
{
    constexpr int P    = K / 2;
    constexpr int OH   = IH / 2, OW = IW / 2;
    constexpr int SPr  = 4 + IW + P;
    constexpr int SP   = (SPr + 3) & ~3;
    constexpr int OC_B = 4 * OCT;
    constexpr int NOCB = OC / OC_B;
    constexpr int RL   = 2 * CPT + 2 * P - 1;
    constexpr int NCH  = IC / ICC;
    constexpr int W4   = IW / 4;
    static_assert(LPT * CPT == OW, "lanes x CPT must cover OW");
    static_assert((ICC & (ICC - 1)) == 0, "ICC pow2");

    __shared__ float sb[K][ICC][SP];

    int b = blockIdx.x;
    const int ocb = b % NOCB; b /= NOCB;
    const int y   = b % OH;   b /= OH;
    const int n   = b;

    const int lane = threadIdx.x & 63;
    const int wav  = threadIdx.x >> 6;
    const int x0   = (lane % LPT) * CPT;   // lanes >= LPT duplicate, epilogue guarded
    const int oc0  = __builtin_amdgcn_readfirstlane(ocb * OC_B + wav * OCT);

    // zero x-halo cols once
    for (int f = threadIdx.x; f < K * ICC * 2 * P; f += 256) {
        int h  = f % (2 * P);
        int t  = f / (2 * P);
        int ic = t & (ICC - 1);
        int r  = t / ICC;
        int col = (h < P) ? (4 - P + h) : (4 + IW + h - P);
        sb[r][ic][col] = 0.0f;
    }

    float acc[OCT][CPT];
#pragma unroll
    for (int j = 0; j < OCT; ++j) {
        float bv = bias[oc0 + j];
#pragma unroll
        for (int cc = 0; cc < CPT; ++cc) acc[j][cc] = bv;
    }

    const float* inn = in + (size_t)n * (size_t)in_nstride;

    for (int ch = 0; ch < NCH; ++ch) {
        __syncthreads();
        // ---- stage tile: float4 interior, per-row predicate only ----
        const float* inb = inn + (size_t)ch * ICC * IH * IW;
        constexpr int SLOTS = K * ICC * W4;
        for (int f = threadIdx.x; f < SLOTS; f += 256) {
            int c4 = f & (W4 - 1);
            int t  = f / W4;
            int ic = t & (ICC - 1);
            int r  = t / ICC;
            int sy = 2 * y - P + r;
            float4 v = make_float4(0.f, 0.f, 0.f, 0.f);
            if (sy >= 0 && sy < IH)
                v = *reinterpret_cast<const float4*>(
                        inb + (size_t)ic * IH * IW + (size_t)sy * IW + 4 * c4);
            *reinterpret_cast<float4*>(&sb[r][ic][4 + 4 * c4]) = v;
        }
        __syncthreads();
        // ---- accumulate ----
        for (int ic = 0; ic < ICC; ++ic) {
            float s[K][RL];
#pragma unroll
            for (int r = 0; r < K; ++r)
#pragma unroll
                for (int k = 0; k < RL; ++k)
                    s[r][k] = sb[r][ic][4 - P + 2 * x0 + k];
            const float* wp = wgt + ((size_t)oc0 * IC + ch * ICC + ic) * (K * K);
#pragma unroll
            for (int j = 0; j < OCT; ++j) {
                float wv[K * K];
#pragma unroll
                for (int k = 0; k < K * K; ++k) wv[k] = wp[(size_t)j * IC * K * K + k];
#pragma unroll
                for (int cc = 0; cc < CPT; ++cc)
#pragma unroll
                    for (int ky = 0; ky < K; ++ky)
#pragma unroll
                        for (int kx = 0; kx < K; ++kx)
                            acc[j][cc] += wv[ky * K + kx] * s[ky][2 * cc + kx];
            }
        }
    }

    if (lane < LPT) {
#pragma unroll
        for (int j = 0; j < OCT; ++j) {
            size_t ob = (((size_t)n * OC + oc0 + j) * OH + y) * OW + x0;
#pragma unroll
            for (int cc = 0; cc < CPT; ++cc) {
                float m  = mem[ob + cc] * DECAYc + acc[j][cc];
                float sp = (m - THRc) > 0.0f ? 1.0f : 0.0f;
                mem[ob + cc] = m - sp * THRc;
                if constexpr (DO_MEAN) {
                    float mv = mean[ob + cc];
                    mean[ob + cc] = mv + (sp - mv) * inv_tf;
                }
                out[ob + cc] = sp;
            }
        }
    }
}

// ---------------- encoder conv dbuf: 3x3 stride-2, s_load weights -----------
template<int IC, int ICC, int OC, int IH, int IW, int CPT, int LPT, int OCT, bool DO_MEAN>
__global__ __launch_bounds__(256) void enc_convdb(
    const float* __restrict__ in, int in_nstride,
    const float* __restrict__ wgt,   // [OC][IC][3][3]
    const float* __restrict__ bias,  // [OC]
    float* __restrict__ mem,
    float* __restrict__ out,
    float* __restrict__ mean,
    float inv_tf)
{
    constexpr int K    = 3;
    constexpr int P    = 1;
    constexpr int OH   = IH / 2, OW = IW / 2;
    constexpr int SPr  = 4 + IW + P;
    constexpr int SP   = (SPr + 3) & ~3;
    constexpr int OC_B = 4 * OCT;
    constexpr int NOCB = OC / OC_B;
    constexpr int RL   = 2 * CPT + 2 * P - 1;
    constexpr int NCH  = IC / ICC;
    constexpr int W4   = IW / 4;
    constexpr int TILE = K * ICC * SP;
    constexpr int SLOTS = K * ICC * W4;
    static_assert(LPT * CPT == OW, "lanes x CPT must cover OW");
    static_assert((ICC & (ICC - 1)) == 0, "ICC pow2");
    static_assert(NCH >= 2, "dbuf needs >=2 chunks");

    __shared__ __align__(16) float sb[2 * TILE];

    int b = blockIdx.x;
    const int ocb = b % NOCB; b /= NOCB;
    const int y   = b % OH;   b /= OH;
    const int n   = b;

    const int lane = threadIdx.x & 63;
    const int wav  = threadIdx.x >> 6;
    const int x0   = (lane % LPT) * CPT;   // lanes >= LPT duplicate, epilogue guarded
    const int oc0  = __builtin_amdgcn_readfirstlane(ocb * OC_B + wav * OCT);

    // zero x-halo cols once, both buffers
    for (int f = threadIdx.x; f < 2 * K * ICC * 2 * P; f += 256) {
        int h   = f % (2 * P);
        int t   = f / (2 * P);
        int ic  = t & (ICC - 1);
        int t2  = t / ICC;
        int r   = t2 % K;
        int buf = t2 / K;
        int col = (h < P) ? (4 - P + h) : (4 + IW + h - P);
        sb[buf * TILE + (r * ICC + ic) * SP + col] = 0.0f;
    }

    float acc[OCT][CPT];
#pragma unroll
    for (int j = 0; j < OCT; ++j) {
        float bv = bias[oc0 + j];
#pragma unroll
        for (int cc = 0; cc < CPT; ++cc) acc[j][cc] = bv;
    }

    const float* inn = in + (size_t)n * (size_t)in_nstride;

    auto stage = [&](int buf, int ch) {
        const float* inb = inn + (size_t)ch * ICC * IH * IW;
        float* dst = sb + buf * TILE;
        for (int f = threadIdx.x; f < SLOTS; f += 256) {
            int c4 = f & (W4 - 1);
            int t  = f / W4;
            int ic = t & (ICC - 1);
            int r  = t / ICC;
            int sy = 2 * y - P + r;
            float4 v = make_float4(0.f, 0.f, 0.f, 0.f);
            if (sy >= 0 && sy < IH)
                v = *reinterpret_cast<const float4*>(
                        inb + (size_t)ic * IH * IW + (size_t)sy * IW + 4 * c4);
            *reinterpret_cast<float4*>(&dst[(r * ICC + ic) * SP + 4 + 4 * c4]) = v;
        }
    };

    stage(0, 0);
    __syncthreads();
    for (int ch = 0; ch < NCH; ++ch) {
        if (ch + 1 < NCH) stage((ch + 1) & 1, ch + 1);   // overlap with compute
        const float* bp = sb + (ch & 1) * TILE;
        for (int ic = 0; ic < ICC; ++ic) {
            float s[K][RL];
#pragma unroll
            for (int r = 0; r < K; ++r)
#pragma unroll
                for (int k = 0; k < RL; ++k)
                    s[r][k] = bp[(r * ICC + ic) * SP + 4 - P + 2 * x0 + k];
            const float* wp = wgt + ((size_t)oc0 * IC + ch * ICC + ic) * (K * K);
#pragma unroll
            for (int j = 0; j < OCT; ++j) {
                float wv[K * K];
#pragma unroll
                for (int k = 0; k < K * K; ++k) wv[k] = wp[(size_t)j * IC * K * K + k];
#pragma unroll
                for (int cc = 0; cc < CPT; ++cc)
#pragma unroll
                    for (int ky = 0; ky < K; ++ky)
#pragma unroll
                        for (int kx = 0; kx < K; ++kx)
                            acc[j][cc] += wv[ky * K + kx] * s[ky][2 * cc + kx];
            }
        }
        __syncthreads();   // stage(ch+1) complete; compute reads of bp done
    }

    if (lane < LPT) {
#pragma unroll
        for (int j = 0; j < OCT; ++j) {
            size_t ob = (((size_t)n * OC + oc0 + j) * OH + y) * OW + x0;
#pragma unroll
            for (int cc = 0; cc < CPT; ++cc) {
                float m  = mem[ob + cc] * DECAYc + acc[j][cc];
                float sp = (m - THRc) > 0.0f ? 1.0f : 0.0f;
                mem[ob + cc] = m - sp * THRc;
                if constexpr (DO_MEAN) {
                    float mv = mean[ob + cc];
                    mean[ob + cc] = mv + (sp - mv) * inv_tf;
                }
                out[ob + cc] = sp;
            }
        }
    }
}

// ---------------- generic conv (flow head only) ------------------------------
template<int IC, int OC, int IH, int IW, int OH, int OW,
         int K, int STRIDE, int PAD, bool UP2, int SKIP_IC,
         bool DO_LIF, bool DO_MEAN>
__global__ __launch_bounds__(256) void conv_fused(
    const float* __restrict__ in, int in_nstride,
    const float* __restrict__ wgt,
    const float* __restrict__ bias,
    float* __restrict__ mem,
    float* __restrict__ out,
    const float* __restrict__ skip_in,
    const float* __restrict__ skip_w,
    float* __restrict__ mean,
    float inv_tf, float outscale)
{
    constexpr int VEC  = 4;
    constexpr int OWV  = OW / VEC;
    constexpr int WSZ  = IC * K * K;
    constexpr int SIH  = UP2 ? IH / 2 : IH;
    constexpr int SIW  = UP2 ? IW / 2 : IW;
    constexpr int RLEN = (VEC - 1) * STRIDE + K;

    __shared__ float sw[WSZ];

    const int bstart = blockIdx.x * 256;
    const int oc = (bstart / (OH * OWV)) % OC;

    for (int i = threadIdx.x; i < WSZ; i += 256) sw[i] = wgt[oc * WSZ + i];
    __syncthreads();

    const int idx = bstart + threadIdx.x;
    const int wx  = idx % OWV;
    int tt        = idx / OWV;
    const int oy  = tt % OH; tt /= OH;
    tt /= OC;
    const int n   = tt;
    const int ox0 = wx * VEC;

    const float bv = bias ? bias[oc] : 0.0f;
    float acc[VEC];
#pragma unroll
    for (int v = 0; v < VEC; ++v) acc[v] = bv;

    const float* inn = in + (size_t)n * (size_t)in_nstride;

    for (int ic = 0; ic < IC; ++ic) {
        const float* inc = inn + (size_t)ic * (SIH * SIW);
#pragma unroll
        for (int ky = 0; ky < K; ++ky) {
            const int uy = oy * STRIDE + ky - PAD;
            const bool rowok = (uy >= 0) & (uy < IH);
            int sy = UP2 ? (uy >> 1) : uy;
            sy = sy < 0 ? 0 : (sy > SIH - 1 ? SIH - 1 : sy);
            const float* __restrict__ row = inc + (size_t)sy * SIW;

            float r[RLEN];
#pragma unroll
            for (int j = 0; j < RLEN; ++j) {
                const int ux = ox0 * STRIDE - PAD + j;
                const bool ok = rowok & (ux >= 0) & (ux < IW);
                int sx = UP2 ? (ux >> 1) : ux;
                sx = sx < 0 ? 0 : (sx > SIW - 1 ? SIW - 1 : sx);
                r[j] = ok ? row[sx] : 0.0f;
            }
#pragma unroll
            for (int kx = 0; kx < K; ++kx) {
                const float wv = sw[(ic * K + ky) * K + kx];
#pragma unroll
                for (int v = 0; v < VEC; ++v)
                    acc[v] += r[v * STRIDE + kx] * wv;
            }
        }
    }

    const size_t obase = ((((size_t)n * OC + oc) * OH) + oy) * (size_t)OW + ox0;
#pragma unroll
    for (int v = 0; v < VEC; ++v) out[obase + v] = acc[v] * outscale;
}

extern "C" void kernel_launch(void* const* d_in, const int* in_sizes, int n_in,
                              void* d_out, int out_size, void* d_ws, size_t ws_size,
                              hipStream_t stream)
{
    const float* x     = (const float*)d_in[0];
    const float* w_e1  = (const float*)d_in[1];
    const float* b_e1  = (const float*)d_in[2];
    const float* w_e2  = (const float*)d_in[3];
    const float* b_e2  = (const float*)d_in[4];
    const float* w_e3  = (const float*)d_in[5];
    const float* b_e3  = (const float*)d_in[6];
    const float* w_d3  = (const float*)d_in[7];
    const float* b_d3  = (const float*)d_in[8];
    const float* w_d2  = (const float*)d_in[9];
    const float* b_d2  = (const float*)d_in[10];
    const float* w_d1  = (const float*)d_in[11];
    const float* b_d1  = (const float*)d_in[12];
    const float* w_sk2 = (const float*)d_in[13];
    const float* w_sk1 = (const float*)d_in[14];
    const float* w_fl  = (const float*)d_in[15];
    const float* b_fl  = (const float*)d_in[16];
    float* outp = (float*)d_out;

    float* ws = (float*)d_ws;
    size_t off = 0;
    auto alloc = [&](size_t nelem) { float* p = ws + off; off += nelem; return p; };

    // persistent state (zeroed each launch)
    float* m1  = alloc(4UL * 32 * 128 * 128);
    float* m2  = alloc(4UL * 64 * 64 * 64);
    float* m3  = alloc(4UL * 128 * 32 * 32);
    float* md3 = alloc(4UL * 64 * 64 * 64);
    float* md2 = alloc(4UL * 32 * 128 * 128);
    float* md1 = alloc(4UL * 32 * 256 * 256);
    float* me1 = alloc(4UL * 32 * 128 * 128);
    float* me2 = alloc(4UL * 64 * 64 * 64);
    const size_t zcount = off;
    // per-timestep activations
    float* s1  = alloc(4UL * 32 * 128 * 128);
    float* s2  = alloc(4UL * 64 * 64 * 64);
    float* s3  = alloc(4UL * 128 * 32 * 32);
    float* d3a = alloc(4UL * 64 * 64 * 64);
    float* d2a = alloc(4UL * 32 * 128 * 128);
    float* d1a = alloc(4UL * 32 * 256 * 256);
    // collapsed decoder weights (+64 floats slack each for prefetch overshoot)
    float* wc3 = alloc(64UL * 128 * 16 + 64);
    float* wc2 = alloc(32UL * 64 * 16 + 64);
    float* wc1 = alloc(32UL * 32 * 16 + 64);
    (void)ws_size; (void)in_sizes; (void)n_in; (void)out_size;

    hipMemsetAsync(d_ws, 0, zcount * sizeof(float), stream);

    prep_collapse<<<(64 * 128 + 255) / 256, 256, 0, stream>>>(w_d3, wc3, 64 * 128);
    prep_collapse<<<(32 * 64 + 255) / 256, 256, 0, stream>>>(w_d2, wc2, 32 * 64);
    prep_collapse<<<(32 * 32 + 255) / 256, 256, 0, stream>>>(w_d1, wc1, 32 * 32);

    for (int t = 0; t < 8; ++t) {
        const float inv_tf = 1.0f / (float)(t + 1);
        const float* xt = x + (size_t)t * 2 * 256 * 256;   // n-stride = T*2*H*W

        // e1: 5x5 s2, 2->32, 256->128, LIF + me1
        enc_conv<2, 2, 32, 256, 256, 5, 2, 64, 2, true>
            <<<4 * 128 * 4, 256, 0, stream>>>(xt, 8 * 2 * 256 * 256, w_e1, b_e1,
                                              m1, s1, me1, inv_tf);
        // e2: 3x3 s2, 32->64, 128->64, LIF + me2. dbuf ICC=8 (26.1KB), grid 2048
        enc_convdb<32, 8, 64, 128, 128, 1, 64, 2, true>
            <<<4 * 64 * 8, 256, 0, stream>>>(s1, 32 * 128 * 128, w_e2, b_e2,
                                             m2, s2, me2, inv_tf);
        // e3: 3x3 s2, 64->128, 64->32, LIF. dbuf ICC=16 (27.6KB), grid 1024
        enc_convdb<64, 16, 128, 64, 64, 1, 32, 4, false>
            <<<4 * 32 * 8, 256, 0, stream>>>(s2, 64 * 64 * 64, w_e3, b_e3,
                                             m3, s3, nullptr, inv_tf);
        // d3: ICC=16 (dbuf 30.7KB), OCT=1, CPT=2, YPB=4, NW=4, DBW=1. grid 512
        dec_conv<128, 16, 64, 32, 32, 2, 4, 1, 4, 64, 8, 1>
            <<<4 * 8 * 16, 256, 0, stream>>>(s3, wc3, b_d3, md3, d3a, me2, w_sk2);
        // d2: ICC=16 (dbuf 36.9KB), OCT=2, CPT=2, YPB=2, NW=4, DBW=0. grid 512
        dec_conv<64, 16, 32, 64, 64, 2, 2, 2, 4, 32, 8, 0>
            <<<4 * 32 * 4, 256, 0, stream>>>(d3a, wc2, b_d2, md2, d2a, me1, w_sk1);
        // d1: ICC=8 (dbuf 34.8KB), OCT=2, CPT=4, YPB=2, LPT=32, DBW=1. grid 1024
        dec_conv<32, 8, 32, 128, 128, 4, 2, 2, 4, 0, 1, 1>
            <<<4 * 64 * 4, 256, 0, stream>>>(d2a, wc1, b_d1, md1,
                                             (t == 7) ? d1a : nullptr, nullptr, nullptr);
        // flow head only at the final timestep
        if (t == 7) {
            conv_fused<32, 2, 256, 256, 256, 256, 3, 1, 1, false, 0, false, false>
                <<<512, 256, 0, stream>>>(d1a, 32 * 256 * 256, w_fl, b_fl,
                                          nullptr, outp, nullptr, nullptr, nullptr, inv_tf, 16.0f);
        }
    }
}